// Round 1
// baseline (1522.945 us; speedup 1.0000x reference)
//
#include <hip/hip_runtime.h>

#define S 3072
#define D 512
#define H 8
#define DK 64
#define DV 64

constexpr float LN_EPS = 1e-6f;

// -------------------- K1: QKV projection --------------------
// x[S,D] @ {Wq,Wk,Wv}[D,512] + b  -> Q/K/V in [H][S][64] layout (Q pre-scaled by 1/8)
// grid (S/8, 6), block 256. Column-block cb covers 256 of the 1536 concat cols.
__global__ void qkv_kernel(const float* __restrict__ x,
                           const float* __restrict__ Wq, const float* __restrict__ bq,
                           const float* __restrict__ Wk, const float* __restrict__ bk,
                           const float* __restrict__ Wv, const float* __restrict__ bv,
                           float* __restrict__ Q, float* __restrict__ K, float* __restrict__ V) {
    __shared__ float xs[8][D];
    const int rb = blockIdx.x;
    const int cb = blockIdx.y;
    const int t  = threadIdx.x;
    const int r0 = rb * 8;
    // stage 8 rows of x (4096 floats, 16/thread, coalesced)
    for (int u = 0; u < 16; ++u) {
        int idx = t + 256 * u;
        xs[idx >> 9][idx & 511] = x[r0 * D + idx];
    }
    __syncthreads();
    const int gc = cb * 256 + t;     // 0..1535
    const int m  = gc >> 9;          // 0:Q 1:K 2:V  (256 | 512 boundaries align)
    const int cc = gc & 511;
    const float* W    = (m == 0) ? Wq : (m == 1) ? Wk : Wv;
    const float* bias = (m == 0) ? bq : (m == 1) ? bk : bv;
    float acc[8];
#pragma unroll
    for (int r = 0; r < 8; ++r) acc[r] = 0.f;
    for (int k = 0; k < D; ++k) {
        float w = W[k * 512 + cc];   // coalesced across threads
#pragma unroll
        for (int r = 0; r < 8; ++r) acc[r] += xs[r][k] * w;
    }
    const float b = bias[cc];
    const int h = cc >> 6, d = cc & 63;
    float* dst = (m == 0) ? Q : (m == 1) ? K : V;
    const float scale = (m == 0) ? 0.125f : 1.0f;   // 1/sqrt(DK) folded into Q
#pragma unroll
    for (int r = 0; r < 8; ++r) {
        dst[(((size_t)h * S + (r0 + r)) << 6) + d] = (acc[r] + b) * scale;
    }
}

// -------------------- K2: logits = Qs @ K^T --------------------
// grid (48, 48, 8), block 256; each thread computes a 4x4 micro-tile.
// LDS rows padded to 65 floats: bank = (row + d) % 32 -> conflict-free.
__global__ void logits_kernel(const float* __restrict__ Q, const float* __restrict__ K,
                              float* __restrict__ attn) {
    __shared__ float qs[64 * 65];
    __shared__ float ks[64 * 65];
    const int ti = blockIdx.x, tj = blockIdx.y, h = blockIdx.z;
    const int t = threadIdx.x;
    const float* Qh = Q + ((size_t)h * S) * 64;
    const float* Kh = K + ((size_t)h * S) * 64;
    for (int u = 0; u < 16; ++u) {
        int idx = t + 256 * u;       // 0..4095
        int r = idx >> 6, d = idx & 63;
        qs[r * 65 + d] = Qh[((size_t)(ti * 64 + r)) * 64 + d];
        ks[r * 65 + d] = Kh[((size_t)(tj * 64 + r)) * 64 + d];
    }
    __syncthreads();
    const int ty = t >> 4, tx = t & 15;
    float acc[4][4] = {};
    for (int d = 0; d < 64; ++d) {
        float a[4], b[4];
#pragma unroll
        for (int i = 0; i < 4; ++i) a[i] = qs[(ty * 4 + i) * 65 + d];
#pragma unroll
        for (int j = 0; j < 4; ++j) b[j] = ks[(tx * 4 + j) * 65 + d];
#pragma unroll
        for (int i = 0; i < 4; ++i)
#pragma unroll
            for (int j = 0; j < 4; ++j)
                acc[i][j] += a[i] * b[j];
    }
    const size_t base = ((size_t)h * S + ti * 64) * S + tj * 64;
#pragma unroll
    for (int i = 0; i < 4; ++i) {
        float4 v = make_float4(acc[i][0], acc[i][1], acc[i][2], acc[i][3]);
        *reinterpret_cast<float4*>(&attn[base + (size_t)(ty * 4 + i) * S + tx * 4]) = v;
    }
}

// -------------------- K3: entmax-1.5 per row (in place) --------------------
// Solves sum((X_i - tau)_+^2) = 1 by guarded Newton from tau0 = -1 (X shifted so max=0,
// halved). f is convex decreasing => monotone convergence, no overshoot.
__global__ void entmax_kernel(float* __restrict__ attn) {
    const int i = blockIdx.x, h = blockIdx.y;
    const int t = threadIdx.x;
    float* row = attn + ((size_t)h * S + i) * S;
    float v[12];
#pragma unroll
    for (int u = 0; u < 12; ++u) v[u] = row[t + 256 * u];

    // row max
    float m = v[0];
#pragma unroll
    for (int u = 1; u < 12; ++u) m = fmaxf(m, v[u]);
    __shared__ float sm[8];
    const int wave = t >> 6, lane = t & 63;
#pragma unroll
    for (int off = 32; off; off >>= 1) m = fmaxf(m, __shfl_down(m, off, 64));
    if (lane == 0) sm[wave] = m;
    __syncthreads();
    m = fmaxf(fmaxf(sm[0], sm[1]), fmaxf(sm[2], sm[3]));

#pragma unroll
    for (int u = 0; u < 12; ++u) v[u] = (v[u] - m) * 0.5f;

    float tau = -1.0f;
    for (int it = 0; it < 30; ++it) {
        float f = 0.f, fp = 0.f;
#pragma unroll
        for (int u = 0; u < 12; ++u) {
            float z = v[u] - tau;
            if (z > 0.f) { f += z * z; fp += z; }
        }
#pragma unroll
        for (int off = 32; off; off >>= 1) {
            f  += __shfl_down(f, off, 64);
            fp += __shfl_down(fp, off, 64);
        }
        __syncthreads();                 // protect sm reuse across iterations
        if (lane == 0) { sm[wave * 2] = f; sm[wave * 2 + 1] = fp; }
        __syncthreads();
        f  = sm[0] + sm[2] + sm[4] + sm[6];
        fp = sm[1] + sm[3] + sm[5] + sm[7];
        float step = (f - 1.0f) / (2.0f * fp + 1e-20f);
        tau += step;
        if (step < 1e-8f) break;         // block-uniform (tau identical on all threads)
    }
#pragma unroll
    for (int u = 0; u < 12; ++u) {
        float z = fmaxf(v[u] - tau, 0.f);
        row[t + 256 * u] = z * z;
    }
}

// -------------------- K4: PV = attn @ V --------------------
// grid (192, 8): 16 rows x 64 dv per block, k-loop over S in 64-chunks.
__global__ void pv_kernel(const float* __restrict__ attn, const float* __restrict__ V,
                          float* __restrict__ AO) {
    __shared__ float as[16][64];
    __shared__ float vs[64][64];
    const int ib = blockIdx.x, h = blockIdx.y;
    const int t = threadIdx.x;
    const int i0 = ib * 16;
    const int tx = t & 63;   // dv
    const int ty = t >> 6;   // row group
    float acc[4] = {};
    const float* Vh = V + ((size_t)h * S) * 64;
    const float* Ah = attn + ((size_t)h * S + i0) * S;
    for (int kc = 0; kc < S; kc += 64) {
#pragma unroll
        for (int u = 0; u < 4; ++u) {
            int idx = t + 256 * u;
            as[idx >> 6][idx & 63] = Ah[(size_t)(idx >> 6) * S + kc + (idx & 63)];
        }
#pragma unroll
        for (int u = 0; u < 16; ++u) {
            int idx = t + 256 * u;
            vs[idx >> 6][idx & 63] = Vh[(size_t)(kc + (idx >> 6)) * 64 + (idx & 63)];
        }
        __syncthreads();
        for (int kk = 0; kk < 64; ++kk) {
            float vv = vs[kk][tx];                 // stride-1 across wave: conflict-free
#pragma unroll
            for (int r = 0; r < 4; ++r)
                acc[r] += as[ty * 4 + r][kk] * vv; // wave-broadcast
        }
        __syncthreads();
    }
#pragma unroll
    for (int r = 0; r < 4; ++r)
        AO[((size_t)h * S + i0 + ty * 4 + r) * 64 + tx] = acc[r];
}

// -------------------- K5: out-proj + residual + LayerNorm --------------------
// grid (S/8), block 256; each thread owns cols (t, t+256) of 8 rows.
__global__ void outproj_ln_kernel(const float* __restrict__ AO, const float* __restrict__ Wo,
                                  const float* __restrict__ bo, const float* __restrict__ x,
                                  const float* __restrict__ gamma, const float* __restrict__ beta,
                                  float* __restrict__ out) {
    __shared__ float as[8][512];
    __shared__ float red[8];
    const int rb = blockIdx.x;
    const int t  = threadIdx.x;
    const int s0 = rb * 8;
    // gather AO ([H][S][64] -> row-major [S][512])
    for (int u = 0; u < 16; ++u) {
        int idx = t + 256 * u;       // 0..4095
        int r = idx >> 9, c = idx & 511;
        int h = c >> 6, d = c & 63;
        as[r][c] = AO[((size_t)h * S + s0 + r) * 64 + d];
    }
    __syncthreads();
    float acc0[8] = {}, acc1[8] = {};
    const int c0 = t, c1 = t + 256;
    for (int k = 0; k < 512; ++k) {
        float w0 = Wo[k * 512 + c0];
        float w1 = Wo[k * 512 + c1];
#pragma unroll
        for (int r = 0; r < 8; ++r) {
            acc0[r] += as[r][k] * w0;
            acc1[r] += as[r][k] * w1;
        }
    }
    const float b0 = bo[c0], b1 = bo[c1];
    const float g0 = gamma[c0], g1 = gamma[c1];
    const float be0 = beta[c0], be1 = beta[c1];
    const int wave = t >> 6, lane = t & 63;
    for (int r = 0; r < 8; ++r) {
        float y0 = acc0[r] + b0 + x[(size_t)(s0 + r) * 512 + c0];
        float y1 = acc1[r] + b1 + x[(size_t)(s0 + r) * 512 + c1];
        float s = y0 + y1, q = y0 * y0 + y1 * y1;
#pragma unroll
        for (int off = 32; off; off >>= 1) {
            s += __shfl_down(s, off, 64);
            q += __shfl_down(q, off, 64);
        }
        __syncthreads();
        if (lane == 0) { red[wave * 2] = s; red[wave * 2 + 1] = q; }
        __syncthreads();
        s = red[0] + red[2] + red[4] + red[6];
        q = red[1] + red[3] + red[5] + red[7];
        float mu  = s * (1.0f / 512.0f);
        float var = q * (1.0f / 512.0f) - mu * mu;
        float inv = rsqrtf(var + LN_EPS);
        out[(size_t)(s0 + r) * 512 + c0] = (y0 - mu) * inv * g0 + be0;
        out[(size_t)(s0 + r) * 512 + c1] = (y1 - mu) * inv * g1 + be1;
    }
}

extern "C" void kernel_launch(void* const* d_in, const int* in_sizes, int n_in,
                              void* d_out, int out_size, void* d_ws, size_t ws_size,
                              hipStream_t stream) {
    const float* x     = (const float*)d_in[0];
    const float* Wq    = (const float*)d_in[1];
    const float* bq    = (const float*)d_in[2];
    const float* Wk    = (const float*)d_in[3];
    const float* bk    = (const float*)d_in[4];
    const float* Wv    = (const float*)d_in[5];
    const float* bv    = (const float*)d_in[6];
    const float* Wo    = (const float*)d_in[7];
    const float* bo    = (const float*)d_in[8];
    const float* gamma = (const float*)d_in[9];
    const float* beta  = (const float*)d_in[10];

    float* out  = (float*)d_out;
    float* attn = out + (size_t)S * D;          // tuple output #2, also logits scratch

    float* Q  = (float*)d_ws;                   // [H][S][64], pre-scaled
    float* K  = Q + (size_t)H * S * DK;
    float* V  = K + (size_t)H * S * DK;
    float* AO = V + (size_t)H * S * DV;         // PV result [H][S][64]

    qkv_kernel<<<dim3(S / 8, 6), 256, 0, stream>>>(x, Wq, bq, Wk, bk, Wv, bv, Q, K, V);
    logits_kernel<<<dim3(48, 48, 8), 256, 0, stream>>>(Q, K, attn);
    entmax_kernel<<<dim3(S, H), 256, 0, stream>>>(attn);
    pv_kernel<<<dim3(192, 8), 256, 0, stream>>>(attn, V, AO);
    outproj_ln_kernel<<<dim3(S / 8), 256, 0, stream>>>(AO, Wo, bo, x, gamma, beta, out);
}

// Round 2
// 1147.039 us; speedup vs baseline: 1.3277x; 1.3277x over previous
//
#include <hip/hip_runtime.h>

#define S 3072
#define D 512
#define H 8
#define DK 64
#define DV 64

constexpr float LN_EPS = 1e-6f;

// -------------------- K1: QKV projection --------------------
// x[S,D] @ {Wq,Wk,Wv}[D,512] + b -> Q/K/V in [H][S][64] (Q pre-scaled by 1/8).
// grid (S/8, 6), block 256. x rows read as UNIFORM float4 loads (scalarized
// by the compiler -> s_load, free broadcast). No LDS.
__global__ void qkv_kernel(const float* __restrict__ x,
                           const float* __restrict__ Wq, const float* __restrict__ bq,
                           const float* __restrict__ Wk, const float* __restrict__ bk,
                           const float* __restrict__ Wv, const float* __restrict__ bv,
                           float* __restrict__ Q, float* __restrict__ K, float* __restrict__ V) {
    const int rb = blockIdx.x;
    const int cb = blockIdx.y;
    const int t  = threadIdx.x;
    const int r0 = rb * 8;
    const int gc = cb * 256 + t;     // 0..1535
    const int m  = gc >> 9;          // 0:Q 1:K 2:V
    const int cc = gc & 511;
    const float* W    = (m == 0) ? Wq : (m == 1) ? Wk : Wv;
    const float* bias = (m == 0) ? bq : (m == 1) ? bk : bv;
    const float4* xf4 = (const float4*)(x + (size_t)r0 * D);   // [8][128] f4

    float acc[8];
#pragma unroll
    for (int r = 0; r < 8; ++r) acc[r] = 0.f;

    for (int k4 = 0; k4 < D / 4; ++k4) {
        float w0 = W[(k4 * 4 + 0) * 512 + cc];
        float w1 = W[(k4 * 4 + 1) * 512 + cc];
        float w2 = W[(k4 * 4 + 2) * 512 + cc];
        float w3 = W[(k4 * 4 + 3) * 512 + cc];
#pragma unroll
        for (int r = 0; r < 8; ++r) {
            float4 xv = xf4[r * (D / 4) + k4];   // uniform -> scalar load
            acc[r] += xv.x * w0 + xv.y * w1 + xv.z * w2 + xv.w * w3;
        }
    }
    const float b = bias[cc];
    const int h = cc >> 6, d = cc & 63;
    float* dst = (m == 0) ? Q : (m == 1) ? K : V;
    const float scale = (m == 0) ? 0.125f : 1.0f;
#pragma unroll
    for (int r = 0; r < 8; ++r)
        dst[(((size_t)h * S + (r0 + r)) << 6) + d] = (acc[r] + b) * scale;
}

// -------------------- K2: logits = Qs @ K^T --------------------
// grid (24, 24, 8), block 256. 128x128 tile, 8x8 per-thread micro-tile.
// LDS as float4 arrays with XOR swizzle on the f4 index to spread the
// row-strided reads across bank groups.
__global__ void logits_kernel(const float* __restrict__ Q, const float* __restrict__ K,
                              float* __restrict__ attn) {
    __shared__ float4 qs4[128 * 16];
    __shared__ float4 ks4[128 * 16];
    const int ti = blockIdx.x, tj = blockIdx.y, h = blockIdx.z;
    const int t = threadIdx.x;
    const float4* Qf4 = (const float4*)(Q + ((size_t)h * S) * 64);
    const float4* Kf4 = (const float4*)(K + ((size_t)h * S) * 64);
#pragma unroll
    for (int u = 0; u < 8; ++u) {
        int idx = t + 256 * u;          // 0..2047
        int r = idx >> 4, d4 = idx & 15;
        int sw = (r * 16 + d4) ^ ((r >> 3) & 7);
        qs4[sw] = Qf4[(size_t)(ti * 128 + r) * 16 + d4];
        ks4[sw] = Kf4[(size_t)(tj * 128 + r) * 16 + d4];
    }
    __syncthreads();
    const int ty = t >> 4, tx = t & 15;   // 8 rows ty*8.., 8 cols tx*8..
    const int ga = ty & 7, gb = tx & 7;
    float acc[8][8] = {};
    for (int d4 = 0; d4 < 16; ++d4) {
        float4 a4[8], b4[8];
#pragma unroll
        for (int i = 0; i < 8; ++i) a4[i] = qs4[((ty * 8 + i) * 16 + d4) ^ ga];
#pragma unroll
        for (int j = 0; j < 8; ++j) b4[j] = ks4[((tx * 8 + j) * 16 + d4) ^ gb];
#pragma unroll
        for (int i = 0; i < 8; ++i)
#pragma unroll
            for (int j = 0; j < 8; ++j)
                acc[i][j] += a4[i].x * b4[j].x + a4[i].y * b4[j].y +
                             a4[i].z * b4[j].z + a4[i].w * b4[j].w;
    }
    const size_t base = ((size_t)h * S + ti * 128) * S + tj * 128;
#pragma unroll
    for (int i = 0; i < 8; ++i) {
        size_t rowoff = base + (size_t)(ty * 8 + i) * S + tx * 8;
        *reinterpret_cast<float4*>(&attn[rowoff])     = make_float4(acc[i][0], acc[i][1], acc[i][2], acc[i][3]);
        *reinterpret_cast<float4*>(&attn[rowoff + 4]) = make_float4(acc[i][4], acc[i][5], acc[i][6], acc[i][7]);
    }
}

// -------------------- K3: entmax-1.5 per row (in place) --------------------
// Root of f(tau) = sum((x/2 - tau)_+^2) = 1 (x shifted so max=0). Convex
// decreasing f => Newton converges from either side (first step lands left of
// tau*, then monotone). Init with the full-support closed form (exact when
// support==n). tau* in [-1, -sqrt(1/3072)] => clamp [-1, -0.01] is safe.
__global__ void entmax_kernel(float* __restrict__ attn) {
    const int i = blockIdx.x, h = blockIdx.y;
    const int t = threadIdx.x;
    float* row = attn + ((size_t)h * S + i) * S;
    float4* rf4 = (float4*)row;
    float v[12];
    {
        float4 w0 = rf4[t], w1 = rf4[t + 256], w2 = rf4[t + 512];
        v[0] = w0.x; v[1] = w0.y; v[2]  = w0.z; v[3]  = w0.w;
        v[4] = w1.x; v[5] = w1.y; v[6]  = w1.z; v[7]  = w1.w;
        v[8] = w2.x; v[9] = w2.y; v[10] = w2.z; v[11] = w2.w;
    }
    float m = v[0], s = v[0], q = v[0] * v[0];
#pragma unroll
    for (int u = 1; u < 12; ++u) { m = fmaxf(m, v[u]); s += v[u]; q += v[u] * v[u]; }

    __shared__ float sm[12];
    __shared__ float sr[8];
    const int wave = t >> 6, lane = t & 63;
#pragma unroll
    for (int off = 32; off; off >>= 1) {
        m = fmaxf(m, __shfl_down(m, off, 64));
        s += __shfl_down(s, off, 64);
        q += __shfl_down(q, off, 64);
    }
    if (lane == 0) { sm[wave * 3] = m; sm[wave * 3 + 1] = s; sm[wave * 3 + 2] = q; }
    __syncthreads();
    m = fmaxf(fmaxf(sm[0], sm[3]), fmaxf(sm[6], sm[9]));
    s = sm[1] + sm[4] + sm[7] + sm[10];
    q = sm[2] + sm[5] + sm[8] + sm[11];

    // shifted/halved values y = (x - m)/2
#pragma unroll
    for (int u = 0; u < 12; ++u) v[u] = (v[u] - m) * 0.5f;

    const float n = (float)S;
    const float mean = (s / n - m) * 0.5f;
    const float msq  = (q - 2.f * m * s + n * m * m) * (0.25f / n);
    const float ss   = n * (msq - mean * mean);
    const float delta = fmaxf((1.f - ss) / n, 0.f);
    float tau = mean - sqrtf(delta);
    tau = fminf(fmaxf(tau, -1.0f), -0.01f);

    for (int it = 0; it < 12; ++it) {
        float f = 0.f, fp = 0.f;
#pragma unroll
        for (int u = 0; u < 12; ++u) {
            float z = v[u] - tau;
            if (z > 0.f) { f += z * z; fp += z; }
        }
#pragma unroll
        for (int off = 32; off; off >>= 1) {
            f  += __shfl_down(f, off, 64);
            fp += __shfl_down(fp, off, 64);
        }
        __syncthreads();
        if (lane == 0) { sr[wave * 2] = f; sr[wave * 2 + 1] = fp; }
        __syncthreads();
        f  = sr[0] + sr[2] + sr[4] + sr[6];
        fp = sr[1] + sr[3] + sr[5] + sr[7];
        float step = (f - 1.0f) / (2.0f * fp + 1e-20f);
        tau = fminf(fmaxf(tau + step, -1.0f), -0.01f);
        if (fabsf(step) < 1e-8f) break;       // block-uniform
    }
#pragma unroll
    for (int u = 0; u < 12; ++u) {
        float z = fmaxf(v[u] - tau, 0.f);
        v[u] = z * z;
    }
    rf4[t]       = make_float4(v[0], v[1], v[2],  v[3]);
    rf4[t + 256] = make_float4(v[4], v[5], v[6],  v[7]);
    rf4[t + 512] = make_float4(v[8], v[9], v[10], v[11]);
}

// -------------------- K4: PV = attn @ V --------------------
// grid (48, 8), block 256. Tile 64 rows x 64 dv, thread = 8 rows x 2 cols.
// A read straight from global (wave-broadcast f4 loads, each element fetched
// once per block); only V staged in LDS (16 KB).
__global__ void pv_kernel(const float* __restrict__ attn, const float* __restrict__ V,
                          float* __restrict__ AO) {
    __shared__ float vs[64][64];
    const int ib = blockIdx.x, h = blockIdx.y;
    const int t = threadIdx.x;
    const int i0 = ib * 64;
    const int tx = t & 31;   // col pair tx*2
    const int ty = t >> 5;   // rows ty*8..ty*8+7
    float acc[8][2] = {};
    const float4* Vf4 = (const float4*)(V + ((size_t)h * S) * 64);
    const float4* Af4 = (const float4*)(attn + ((size_t)h * S + i0) * S);
    const float2* vs2 = (const float2*)vs;

    for (int kc = 0; kc < S; kc += 64) {
#pragma unroll
        for (int u = 0; u < 4; ++u) {
            int idx = t + 256 * u;             // 0..1023 f4
            int kk = idx >> 4, d4 = idx & 15;
            ((float4*)vs)[idx] = Vf4[(size_t)(kc + kk) * 16 + d4];
        }
        __syncthreads();
        for (int k4 = 0; k4 < 16; ++k4) {
            float4 a4[8];
#pragma unroll
            for (int r = 0; r < 8; ++r)
                a4[r] = Af4[(size_t)(ty * 8 + r) * (S / 4) + (kc >> 2) + k4];
            float2 b0 = vs2[(k4 * 4 + 0) * 32 + tx];
            float2 b1 = vs2[(k4 * 4 + 1) * 32 + tx];
            float2 b2 = vs2[(k4 * 4 + 2) * 32 + tx];
            float2 b3 = vs2[(k4 * 4 + 3) * 32 + tx];
#pragma unroll
            for (int r = 0; r < 8; ++r) {
                acc[r][0] += a4[r].x * b0.x + a4[r].y * b1.x + a4[r].z * b2.x + a4[r].w * b3.x;
                acc[r][1] += a4[r].x * b0.y + a4[r].y * b1.y + a4[r].z * b2.y + a4[r].w * b3.y;
            }
        }
        __syncthreads();
    }
#pragma unroll
    for (int r = 0; r < 8; ++r) {
        float2 o = make_float2(acc[r][0], acc[r][1]);
        *reinterpret_cast<float2*>(&AO[((size_t)h * S + i0 + ty * 8 + r) * 64 + tx * 2]) = o;
    }
}

// -------------------- K5: out-proj + residual + LayerNorm --------------------
// grid (S/8), block 256. AO rows read as UNIFORM f4 loads (scalarized); no LDS
// gather. Each thread owns cols (t, t+256) of 8 rows.
__global__ void outproj_ln_kernel(const float* __restrict__ AO, const float* __restrict__ Wo,
                                  const float* __restrict__ bo, const float* __restrict__ x,
                                  const float* __restrict__ gamma, const float* __restrict__ beta,
                                  float* __restrict__ out) {
    __shared__ float red[8];
    const int rb = blockIdx.x;
    const int t  = threadIdx.x;
    const int s0 = rb * 8;
    float acc0[8] = {}, acc1[8] = {};
    const int c0 = t, c1 = t + 256;
    const float4* AOf4 = (const float4*)AO;
    for (int k4 = 0; k4 < 128; ++k4) {
        int k = k4 * 4;
        int h = k >> 6, d4 = (k & 63) >> 2;
        float w00 = Wo[(k + 0) * 512 + c0], w10 = Wo[(k + 0) * 512 + c1];
        float w01 = Wo[(k + 1) * 512 + c0], w11 = Wo[(k + 1) * 512 + c1];
        float w02 = Wo[(k + 2) * 512 + c0], w12 = Wo[(k + 2) * 512 + c1];
        float w03 = Wo[(k + 3) * 512 + c0], w13 = Wo[(k + 3) * 512 + c1];
#pragma unroll
        for (int r = 0; r < 8; ++r) {
            float4 a = AOf4[((size_t)h * S + s0 + r) * 16 + d4];   // uniform
            acc0[r] += a.x * w00 + a.y * w01 + a.z * w02 + a.w * w03;
            acc1[r] += a.x * w10 + a.y * w11 + a.z * w12 + a.w * w13;
        }
    }
    const float b0 = bo[c0], b1 = bo[c1];
    const float g0 = gamma[c0], g1 = gamma[c1];
    const float be0 = beta[c0], be1 = beta[c1];
    const int wave = t >> 6, lane = t & 63;
    for (int r = 0; r < 8; ++r) {
        float y0 = acc0[r] + b0 + x[(size_t)(s0 + r) * 512 + c0];
        float y1 = acc1[r] + b1 + x[(size_t)(s0 + r) * 512 + c1];
        float s = y0 + y1, qq = y0 * y0 + y1 * y1;
#pragma unroll
        for (int off = 32; off; off >>= 1) {
            s  += __shfl_down(s, off, 64);
            qq += __shfl_down(qq, off, 64);
        }
        __syncthreads();
        if (lane == 0) { red[wave * 2] = s; red[wave * 2 + 1] = qq; }
        __syncthreads();
        s  = red[0] + red[2] + red[4] + red[6];
        qq = red[1] + red[3] + red[5] + red[7];
        float mu  = s * (1.0f / 512.0f);
        float var = qq * (1.0f / 512.0f) - mu * mu;
        float inv = rsqrtf(var + LN_EPS);
        out[(size_t)(s0 + r) * 512 + c0] = (y0 - mu) * inv * g0 + be0;
        out[(size_t)(s0 + r) * 512 + c1] = (y1 - mu) * inv * g1 + be1;
    }
}

extern "C" void kernel_launch(void* const* d_in, const int* in_sizes, int n_in,
                              void* d_out, int out_size, void* d_ws, size_t ws_size,
                              hipStream_t stream) {
    const float* x     = (const float*)d_in[0];
    const float* Wq    = (const float*)d_in[1];
    const float* bq    = (const float*)d_in[2];
    const float* Wk    = (const float*)d_in[3];
    const float* bk    = (const float*)d_in[4];
    const float* Wv    = (const float*)d_in[5];
    const float* bv    = (const float*)d_in[6];
    const float* Wo    = (const float*)d_in[7];
    const float* bo    = (const float*)d_in[8];
    const float* gamma = (const float*)d_in[9];
    const float* beta  = (const float*)d_in[10];

    float* out  = (float*)d_out;
    float* attn = out + (size_t)S * D;          // tuple output #2, also logits scratch

    float* Q  = (float*)d_ws;                   // [H][S][64], pre-scaled
    float* K  = Q + (size_t)H * S * DK;
    float* V  = K + (size_t)H * S * DK;
    float* AO = V + (size_t)H * S * DV;         // PV result [H][S][64]

    qkv_kernel<<<dim3(S / 8, 6), 256, 0, stream>>>(x, Wq, bq, Wk, bk, Wv, bv, Q, K, V);
    logits_kernel<<<dim3(24, 24, 8), 256, 0, stream>>>(Q, K, attn);
    entmax_kernel<<<dim3(S, H), 256, 0, stream>>>(attn);
    pv_kernel<<<dim3(48, 8), 256, 0, stream>>>(attn, V, AO);
    outproj_ln_kernel<<<dim3(S / 8), 256, 0, stream>>>(AO, Wo, bo, x, gamma, beta, out);
}

// Round 3
// 589.889 us; speedup vs baseline: 2.5817x; 1.9445x over previous
//
#include <hip/hip_runtime.h>

#define S 3072
#define D 512
#define H 8

constexpr float LN_EPS = 1e-6f;

typedef __attribute__((ext_vector_type(8))) short bf16x8;   // 8 bf16 = 4 VGPRs
typedef __attribute__((ext_vector_type(4))) float f32x4;    // MFMA C/D frag

__device__ __forceinline__ short f2bf(float f) {            // RNE fp32->bf16
    unsigned int u = __builtin_bit_cast(unsigned int, f);
    u += 0x7FFFu + ((u >> 16) & 1u);
    return (short)(u >> 16);
}

// -------------------- K1: QKV projection --------------------
// x[S,D] @ {Wq,Wk,Wv}[D,512] + b -> bf16 Q,K in [H][S][64] (Q pre-scaled by
// 1/8) and bf16 V^T in [H][64][S]. grid (S/8, 6), block 256; x rows read as
// uniform float4 (scalarized), W coalesced.
__global__ void qkv_kernel(const float* __restrict__ x,
                           const float* __restrict__ Wq, const float* __restrict__ bq,
                           const float* __restrict__ Wk, const float* __restrict__ bk,
                           const float* __restrict__ Wv, const float* __restrict__ bv,
                           short* __restrict__ Qb, short* __restrict__ Kb,
                           short* __restrict__ Vt) {
    const int rb = blockIdx.x;
    const int cb = blockIdx.y;
    const int t  = threadIdx.x;
    const int r0 = rb * 8;
    const int gc = cb * 256 + t;     // 0..1535
    const int m  = gc >> 9;          // 0:Q 1:K 2:V
    const int cc = gc & 511;
    const float* W    = (m == 0) ? Wq : (m == 1) ? Wk : Wv;
    const float* bias = (m == 0) ? bq : (m == 1) ? bk : bv;
    const float4* xf4 = (const float4*)(x + (size_t)r0 * D);

    float acc[8];
#pragma unroll
    for (int r = 0; r < 8; ++r) acc[r] = 0.f;

    for (int k4 = 0; k4 < D / 4; ++k4) {
        float w0 = W[(k4 * 4 + 0) * 512 + cc];
        float w1 = W[(k4 * 4 + 1) * 512 + cc];
        float w2 = W[(k4 * 4 + 2) * 512 + cc];
        float w3 = W[(k4 * 4 + 3) * 512 + cc];
#pragma unroll
        for (int r = 0; r < 8; ++r) {
            float4 xv = xf4[r * (D / 4) + k4];   // uniform -> s_load broadcast
            acc[r] += xv.x * w0 + xv.y * w1 + xv.z * w2 + xv.w * w3;
        }
    }
    const float b = bias[cc];
    const int h = cc >> 6, d = cc & 63;
    const float scale = (m == 0) ? 0.125f : 1.0f;
#pragma unroll
    for (int r = 0; r < 8; ++r) {
        float val = (acc[r] + b) * scale;
        if (m == 0)      Qb[(((size_t)h * S + (r0 + r)) << 6) + d] = f2bf(val);
        else if (m == 1) Kb[(((size_t)h * S + (r0 + r)) << 6) + d] = f2bf(val);
        else             Vt[((size_t)h * 64 + d) * S + (r0 + r)]   = f2bf(val);
    }
}

// -------------------- K2: logits = Qs @ K^T (MFMA) --------------------
// grid (24, 24, 8), block 256 = 4 waves in 2x2; 128x128 block tile, 64x64 per
// wave = 4x4 MFMA tiles of 16x16x32, K=64 in 2 k-steps. Fragments loaded
// directly from global: lane l -> row (l&15), k-group (l>>4)*8, contiguous 16B.
__global__ void logits_kernel(const short* __restrict__ Qb, const short* __restrict__ Kb,
                              float* __restrict__ attn) {
    const int ti = blockIdx.x, tj = blockIdx.y, h = blockIdx.z;
    const int t = threadIdx.x;
    const int w = t >> 6, l = t & 63;
    const int wr = w >> 1, wc = w & 1;
    const int lr = l & 15, lk = l >> 4;
    const short* Qh = Qb + ((size_t)h * S) * 64;
    const short* Kh = Kb + ((size_t)h * S) * 64;
    const int ar0 = ti * 128 + wr * 64 + lr;
    const int br0 = tj * 128 + wc * 64 + lr;

    f32x4 acc[4][4];
#pragma unroll
    for (int i = 0; i < 4; ++i)
#pragma unroll
        for (int j = 0; j < 4; ++j) acc[i][j] = (f32x4){0.f, 0.f, 0.f, 0.f};

#pragma unroll
    for (int s = 0; s < 2; ++s) {
        bf16x8 af[4], bf_[4];
#pragma unroll
        for (int i = 0; i < 4; ++i)
            af[i] = *(const bf16x8*)(Qh + (size_t)(ar0 + i * 16) * 64 + s * 32 + lk * 8);
#pragma unroll
        for (int j = 0; j < 4; ++j)
            bf_[j] = *(const bf16x8*)(Kh + (size_t)(br0 + j * 16) * 64 + s * 32 + lk * 8);
#pragma unroll
        for (int i = 0; i < 4; ++i)
#pragma unroll
            for (int j = 0; j < 4; ++j)
                acc[i][j] = __builtin_amdgcn_mfma_f32_16x16x32_bf16(af[i], bf_[j], acc[i][j], 0, 0, 0);
    }
    // D layout: col = lane&15, row = (lane>>4)*4 + reg  [guide §3, m89-verified]
    const size_t obase = ((size_t)h * S + ti * 128 + wr * 64) * S + tj * 128 + wc * 64;
#pragma unroll
    for (int i = 0; i < 4; ++i)
#pragma unroll
        for (int r = 0; r < 4; ++r) {
            size_t rowoff = obase + (size_t)(i * 16 + lk * 4 + r) * S + lr;
#pragma unroll
            for (int j = 0; j < 4; ++j)
                attn[rowoff + j * 16] = acc[i][j][r];
        }
}

// -------------------- K3: entmax-1.5 per row (in place, fp32) --------------------
__global__ void entmax_kernel(float* __restrict__ attn) {
    const int i = blockIdx.x, h = blockIdx.y;
    const int t = threadIdx.x;
    float* row = attn + ((size_t)h * S + i) * S;
    float4* rf4 = (float4*)row;
    float v[12];
    {
        float4 w0 = rf4[t], w1 = rf4[t + 256], w2 = rf4[t + 512];
        v[0] = w0.x; v[1] = w0.y; v[2]  = w0.z; v[3]  = w0.w;
        v[4] = w1.x; v[5] = w1.y; v[6]  = w1.z; v[7]  = w1.w;
        v[8] = w2.x; v[9] = w2.y; v[10] = w2.z; v[11] = w2.w;
    }
    float m = v[0], s = v[0], q = v[0] * v[0];
#pragma unroll
    for (int u = 1; u < 12; ++u) { m = fmaxf(m, v[u]); s += v[u]; q += v[u] * v[u]; }

    __shared__ float sm[12];
    __shared__ float sr[8];
    const int wave = t >> 6, lane = t & 63;
#pragma unroll
    for (int off = 32; off; off >>= 1) {
        m = fmaxf(m, __shfl_down(m, off, 64));
        s += __shfl_down(s, off, 64);
        q += __shfl_down(q, off, 64);
    }
    if (lane == 0) { sm[wave * 3] = m; sm[wave * 3 + 1] = s; sm[wave * 3 + 2] = q; }
    __syncthreads();
    m = fmaxf(fmaxf(sm[0], sm[3]), fmaxf(sm[6], sm[9]));
    s = sm[1] + sm[4] + sm[7] + sm[10];
    q = sm[2] + sm[5] + sm[8] + sm[11];

#pragma unroll
    for (int u = 0; u < 12; ++u) v[u] = (v[u] - m) * 0.5f;

    const float n = (float)S;
    const float mean = (s / n - m) * 0.5f;
    const float msq  = (q - 2.f * m * s + n * m * m) * (0.25f / n);
    const float ss   = n * (msq - mean * mean);
    const float delta = fmaxf((1.f - ss) / n, 0.f);
    float tau = mean - sqrtf(delta);
    tau = fminf(fmaxf(tau, -1.0f), -0.01f);

    for (int it = 0; it < 12; ++it) {
        float f = 0.f, fp = 0.f;
#pragma unroll
        for (int u = 0; u < 12; ++u) {
            float z = v[u] - tau;
            if (z > 0.f) { f += z * z; fp += z; }
        }
#pragma unroll
        for (int off = 32; off; off >>= 1) {
            f  += __shfl_down(f, off, 64);
            fp += __shfl_down(fp, off, 64);
        }
        __syncthreads();
        if (lane == 0) { sr[wave * 2] = f; sr[wave * 2 + 1] = fp; }
        __syncthreads();
        f  = sr[0] + sr[2] + sr[4] + sr[6];
        fp = sr[1] + sr[3] + sr[5] + sr[7];
        float step = (f - 1.0f) / (2.0f * fp + 1e-20f);
        tau = fminf(fmaxf(tau + step, -1.0f), -0.01f);
        if (fabsf(step) < 1e-8f) break;       // block-uniform
    }
#pragma unroll
    for (int u = 0; u < 12; ++u) {
        float z = fmaxf(v[u] - tau, 0.f);
        v[u] = z * z;
    }
    rf4[t]       = make_float4(v[0], v[1], v[2],  v[3]);
    rf4[t + 256] = make_float4(v[4], v[5], v[6],  v[7]);
    rf4[t + 512] = make_float4(v[8], v[9], v[10], v[11]);
}

// -------------------- K4: PV = attn @ V (MFMA) --------------------
// grid (48, 2, 8), block 256 = 4 waves. Block = 64 rows; wave = 16 rows x 64
// dv; k-split 2 across blockIdx.y (partial sums in AO[ks]). A loaded fp32 from
// attn + converted in-register to bf16; B from V^T bf16 (contiguous per lane).
__global__ void pv_kernel(const float* __restrict__ attn, const short* __restrict__ Vt,
                          float* __restrict__ AO) {
    const int mb = blockIdx.x, ks = blockIdx.y, h = blockIdx.z;
    const int t = threadIdx.x;
    const int w = t >> 6, l = t & 63;
    const int lr = l & 15, lk = l >> 4;
    const int arow = mb * 64 + w * 16 + lr;
    const float* Ar = attn + ((size_t)h * S + arow) * S + ks * (S / 2) + lk * 8;
    const short* Vh = Vt + (size_t)h * 64 * S + ks * (S / 2) + lk * 8;

    f32x4 acc[4];
#pragma unroll
    for (int j = 0; j < 4; ++j) acc[j] = (f32x4){0.f, 0.f, 0.f, 0.f};

    for (int st = 0; st < 48; ++st) {
        const float4* ap = (const float4*)(Ar + st * 32);
        float4 a0 = ap[0], a1 = ap[1];
        bf16x8 a;
        a[0] = f2bf(a0.x); a[1] = f2bf(a0.y); a[2] = f2bf(a0.z); a[3] = f2bf(a0.w);
        a[4] = f2bf(a1.x); a[5] = f2bf(a1.y); a[6] = f2bf(a1.z); a[7] = f2bf(a1.w);
#pragma unroll
        for (int j = 0; j < 4; ++j) {
            bf16x8 b = *(const bf16x8*)(Vh + (size_t)(j * 16 + lr) * S + st * 32);
            acc[j] = __builtin_amdgcn_mfma_f32_16x16x32_bf16(a, b, acc[j], 0, 0, 0);
        }
    }
    float* AOk = AO + (size_t)ks * ((size_t)H * S * 64)
                    + ((size_t)h * S + mb * 64 + w * 16) * 64;
#pragma unroll
    for (int j = 0; j < 4; ++j)
#pragma unroll
        for (int r = 0; r < 4; ++r)
            AOk[(size_t)(lk * 4 + r) * 64 + j * 16 + lr] = acc[j][r];
}

// -------------------- K5: out-proj + residual + LayerNorm --------------------
// grid (S/8), block 256. AO partials (2 k-split buffers) read as uniform f4
// loads and summed. Each thread owns cols (t, t+256) of 8 rows.
__global__ void outproj_ln_kernel(const float* __restrict__ AO, const float* __restrict__ Wo,
                                  const float* __restrict__ bo, const float* __restrict__ x,
                                  const float* __restrict__ gamma, const float* __restrict__ beta,
                                  float* __restrict__ out) {
    __shared__ float red[8];
    const int rb = blockIdx.x;
    const int t  = threadIdx.x;
    const int s0 = rb * 8;
    float acc0[8] = {}, acc1[8] = {};
    const int c0 = t, c1 = t + 256;
    const float4* A0 = (const float4*)AO;
    const float4* A1 = A0 + (size_t)H * S * 16;
    for (int k4 = 0; k4 < 128; ++k4) {
        int k = k4 * 4;
        int h = k >> 6, d4 = (k & 63) >> 2;
        float w00 = Wo[(k + 0) * 512 + c0], w10 = Wo[(k + 0) * 512 + c1];
        float w01 = Wo[(k + 1) * 512 + c0], w11 = Wo[(k + 1) * 512 + c1];
        float w02 = Wo[(k + 2) * 512 + c0], w12 = Wo[(k + 2) * 512 + c1];
        float w03 = Wo[(k + 3) * 512 + c0], w13 = Wo[(k + 3) * 512 + c1];
#pragma unroll
        for (int r = 0; r < 8; ++r) {
            size_t off = ((size_t)h * S + s0 + r) * 16 + d4;    // uniform
            float4 p = A0[off], q = A1[off];
            float ax = p.x + q.x, ay = p.y + q.y, az = p.z + q.z, aw = p.w + q.w;
            acc0[r] += ax * w00 + ay * w01 + az * w02 + aw * w03;
            acc1[r] += ax * w10 + ay * w11 + az * w12 + aw * w13;
        }
    }
    const float b0 = bo[c0], b1 = bo[c1];
    const float g0 = gamma[c0], g1 = gamma[c1];
    const float be0 = beta[c0], be1 = beta[c1];
    const int wave = t >> 6, lane = t & 63;
    for (int r = 0; r < 8; ++r) {
        float y0 = acc0[r] + b0 + x[(size_t)(s0 + r) * 512 + c0];
        float y1 = acc1[r] + b1 + x[(size_t)(s0 + r) * 512 + c1];
        float s = y0 + y1, qq = y0 * y0 + y1 * y1;
#pragma unroll
        for (int off = 32; off; off >>= 1) {
            s  += __shfl_down(s, off, 64);
            qq += __shfl_down(qq, off, 64);
        }
        __syncthreads();
        if (lane == 0) { red[wave * 2] = s; red[wave * 2 + 1] = qq; }
        __syncthreads();
        s  = red[0] + red[2] + red[4] + red[6];
        qq = red[1] + red[3] + red[5] + red[7];
        float mu  = s * (1.0f / 512.0f);
        float var = qq * (1.0f / 512.0f) - mu * mu;
        float inv = rsqrtf(var + LN_EPS);
        out[(size_t)(s0 + r) * 512 + c0] = (y0 - mu) * inv * g0 + be0;
        out[(size_t)(s0 + r) * 512 + c1] = (y1 - mu) * inv * g1 + be1;
    }
}

extern "C" void kernel_launch(void* const* d_in, const int* in_sizes, int n_in,
                              void* d_out, int out_size, void* d_ws, size_t ws_size,
                              hipStream_t stream) {
    const float* x     = (const float*)d_in[0];
    const float* Wq    = (const float*)d_in[1];
    const float* bq    = (const float*)d_in[2];
    const float* Wk    = (const float*)d_in[3];
    const float* bk    = (const float*)d_in[4];
    const float* Wv    = (const float*)d_in[5];
    const float* bv    = (const float*)d_in[6];
    const float* Wo    = (const float*)d_in[7];
    const float* bo    = (const float*)d_in[8];
    const float* gamma = (const float*)d_in[9];
    const float* beta  = (const float*)d_in[10];

    float* out  = (float*)d_out;
    float* attn = out + (size_t)S * D;          // tuple output #2, logits scratch

    short* Qb = (short*)d_ws;                   // [H][S][64] bf16, pre-scaled
    short* Kb = Qb + (size_t)H * S * 64;        // [H][S][64] bf16
    short* Vt = Kb + (size_t)H * S * 64;        // [H][64][S] bf16 (transposed)
    float* AO = (float*)(Vt + (size_t)H * 64 * S);   // 2 x [H][S][64] f32 partials

    qkv_kernel<<<dim3(S / 8, 6), 256, 0, stream>>>(x, Wq, bq, Wk, bk, Wv, bv, Qb, Kb, Vt);
    logits_kernel<<<dim3(24, 24, 8), 256, 0, stream>>>(Qb, Kb, attn);
    entmax_kernel<<<dim3(S, H), 256, 0, stream>>>(attn);
    pv_kernel<<<dim3(48, 2, 8), 256, 0, stream>>>(attn, Vt, AO);
    outproj_ln_kernel<<<dim3(S / 8), 256, 0, stream>>>(AO, Wo, bo, x, gamma, beta, out);
}

// Round 4
// 550.350 us; speedup vs baseline: 2.7672x; 1.0718x over previous
//
#include <hip/hip_runtime.h>

#define S 3072
#define D 512
#define H 8

constexpr float LN_EPS = 1e-6f;

typedef __attribute__((ext_vector_type(8))) short bf16x8;   // 8 bf16 = 4 VGPRs
typedef __attribute__((ext_vector_type(4))) float f32x4;    // MFMA C/D frag

__device__ __forceinline__ short f2bf(float f) {            // RNE fp32->bf16
    unsigned int u = __builtin_bit_cast(unsigned int, f);
    u += 0x7FFFu + ((u >> 16) & 1u);
    return (short)(u >> 16);
}

// pack two fp32 into two truncated bf16 in one v_perm_b32
__device__ __forceinline__ unsigned pack_bf_trunc(float lo, float hi) {
    return __builtin_amdgcn_perm(__builtin_bit_cast(unsigned, hi),
                                 __builtin_bit_cast(unsigned, lo), 0x07060302u);
}

// -------------------- K1: QKV projection --------------------
// x[S,D] @ {Wq,Wk,Wv}[D,512] + b -> bf16 Q,K in [H][S][64] (Q pre-scaled by
// 1/8) and bf16 V^T in [H][64][S]. grid (S/8, 6), block 256.
__global__ void qkv_kernel(const float* __restrict__ x,
                           const float* __restrict__ Wq, const float* __restrict__ bq,
                           const float* __restrict__ Wk, const float* __restrict__ bk,
                           const float* __restrict__ Wv, const float* __restrict__ bv,
                           short* __restrict__ Qb, short* __restrict__ Kb,
                           short* __restrict__ Vt) {
    const int rb = blockIdx.x;
    const int cb = blockIdx.y;
    const int t  = threadIdx.x;
    const int r0 = rb * 8;
    const int gc = cb * 256 + t;     // 0..1535
    const int m  = gc >> 9;          // 0:Q 1:K 2:V
    const int cc = gc & 511;
    const float* W    = (m == 0) ? Wq : (m == 1) ? Wk : Wv;
    const float* bias = (m == 0) ? bq : (m == 1) ? bk : bv;
    const float4* xf4 = (const float4*)(x + (size_t)r0 * D);

    float acc[8];
#pragma unroll
    for (int r = 0; r < 8; ++r) acc[r] = 0.f;

    for (int k4 = 0; k4 < D / 4; ++k4) {
        float w0 = W[(k4 * 4 + 0) * 512 + cc];
        float w1 = W[(k4 * 4 + 1) * 512 + cc];
        float w2 = W[(k4 * 4 + 2) * 512 + cc];
        float w3 = W[(k4 * 4 + 3) * 512 + cc];
#pragma unroll
        for (int r = 0; r < 8; ++r) {
            float4 xv = xf4[r * (D / 4) + k4];   // uniform -> s_load broadcast
            acc[r] += xv.x * w0 + xv.y * w1 + xv.z * w2 + xv.w * w3;
        }
    }
    const float b = bias[cc];
    const int h = cc >> 6, d = cc & 63;
    const float scale = (m == 0) ? 0.125f : 1.0f;
#pragma unroll
    for (int r = 0; r < 8; ++r) {
        float val = (acc[r] + b) * scale;
        if (m == 0)      Qb[(((size_t)h * S + (r0 + r)) << 6) + d] = f2bf(val);
        else if (m == 1) Kb[(((size_t)h * S + (r0 + r)) << 6) + d] = f2bf(val);
        else             Vt[((size_t)h * 64 + d) * S + (r0 + r)]   = f2bf(val);
    }
}

// -------------------- K2: logits = Qs @ K^T (MFMA) --------------------
// grid (24, 24, 8), block 256 = 4 waves in 2x2; 128x128 tile, 64x64 per wave.
__global__ void logits_kernel(const short* __restrict__ Qb, const short* __restrict__ Kb,
                              float* __restrict__ attn) {
    const int ti = blockIdx.x, tj = blockIdx.y, h = blockIdx.z;
    const int t = threadIdx.x;
    const int w = t >> 6, l = t & 63;
    const int wr = w >> 1, wc = w & 1;
    const int lr = l & 15, lk = l >> 4;
    const short* Qh = Qb + ((size_t)h * S) * 64;
    const short* Kh = Kb + ((size_t)h * S) * 64;
    const int ar0 = ti * 128 + wr * 64 + lr;
    const int br0 = tj * 128 + wc * 64 + lr;

    f32x4 acc[4][4];
#pragma unroll
    for (int i = 0; i < 4; ++i)
#pragma unroll
        for (int j = 0; j < 4; ++j) acc[i][j] = (f32x4){0.f, 0.f, 0.f, 0.f};

#pragma unroll
    for (int s = 0; s < 2; ++s) {
        bf16x8 af[4], bf_[4];
#pragma unroll
        for (int i = 0; i < 4; ++i)
            af[i] = *(const bf16x8*)(Qh + (size_t)(ar0 + i * 16) * 64 + s * 32 + lk * 8);
#pragma unroll
        for (int j = 0; j < 4; ++j)
            bf_[j] = *(const bf16x8*)(Kh + (size_t)(br0 + j * 16) * 64 + s * 32 + lk * 8);
#pragma unroll
        for (int i = 0; i < 4; ++i)
#pragma unroll
            for (int j = 0; j < 4; ++j)
                acc[i][j] = __builtin_amdgcn_mfma_f32_16x16x32_bf16(af[i], bf_[j], acc[i][j], 0, 0, 0);
    }
    // D layout: col = lane&15, row = (lane>>4)*4 + reg
    const size_t obase = ((size_t)h * S + ti * 128 + wr * 64) * S + tj * 128 + wc * 64;
#pragma unroll
    for (int i = 0; i < 4; ++i)
#pragma unroll
        for (int r = 0; r < 4; ++r) {
            size_t rowoff = obase + (size_t)(i * 16 + lk * 4 + r) * S + lr;
#pragma unroll
            for (int j = 0; j < 4; ++j)
                attn[rowoff + j * 16] = acc[i][j][r];
        }
}

// -------------------- K3: entmax-1.5 per row (in place, fp32) --------------------
// Solve sum((w - c)_+^2) = 1, w = (x-m)/2, via support-exact quadratic steps
// (Michelot-style): given f=sum z+^2, fp=sum z+, n=|support| at threshold c,
// the exact root under fixed support is c += (fp - sqrt(fp^2 - n(f-1)))/n.
// Support strictly shrinks -> finite convergence (typically 2-3 iters).
__global__ void entmax_kernel(float* __restrict__ attn) {
    const int i = blockIdx.x, h = blockIdx.y;
    const int t = threadIdx.x;
    float* row = attn + ((size_t)h * S + i) * S;
    float4* rf4 = (float4*)row;
    float w[12];
    {
        float4 w0 = rf4[t], w1 = rf4[t + 256], w2 = rf4[t + 512];
        w[0] = w0.x; w[1] = w0.y; w[2]  = w0.z; w[3]  = w0.w;
        w[4] = w1.x; w[5] = w1.y; w[6]  = w1.z; w[7]  = w1.w;
        w[8] = w2.x; w[9] = w2.y; w[10] = w2.z; w[11] = w2.w;
    }
    // row max
    float m = w[0];
#pragma unroll
    for (int u = 1; u < 12; ++u) m = fmaxf(m, w[u]);
    __shared__ float sm[4];
    __shared__ float sr[12];
    const int wave = t >> 6, lane = t & 63;
#pragma unroll
    for (int off = 32; off; off >>= 1) m = fmaxf(m, __shfl_down(m, off, 64));
    if (lane == 0) sm[wave] = m;
    __syncthreads();
    m = fmaxf(fmaxf(sm[0], sm[1]), fmaxf(sm[2], sm[3]));

    // w = (x - m)/2 shifted into w-space; threshold c starts at lower bound
#pragma unroll
    for (int u = 0; u < 12; ++u) w[u] = w[u] * 0.5f;
    float c = m * 0.5f - 1.0f;        // c* >= m/2 - 1 always

    for (int it = 0; it < 8; ++it) {
        float f = 0.f, fp = 0.f;
        int cnt = 0;
#pragma unroll
        for (int u = 0; u < 12; ++u) {
            float z = w[u] - c;
            float zc = fmaxf(z, 0.f);
            f  = fmaf(zc, zc, f);
            fp += zc;
            cnt += (z > 0.f) ? 1 : 0;
        }
        float cf = (float)cnt;
#pragma unroll
        for (int off = 32; off; off >>= 1) {
            f  += __shfl_down(f, off, 64);
            fp += __shfl_down(fp, off, 64);
            cf += __shfl_down(cf, off, 64);
        }
        __syncthreads();                 // protect sr reuse across iterations
        if (lane == 0) { sr[wave * 3] = f; sr[wave * 3 + 1] = fp; sr[wave * 3 + 2] = cf; }
        __syncthreads();
        f  = sr[0] + sr[3] + sr[6] + sr[9];
        fp = sr[1] + sr[4] + sr[7] + sr[10];
        float n = fmaxf(sr[2] + sr[5] + sr[8] + sr[11], 1.0f);
        float disc = fmaxf(fp * fp - n * (f - 1.0f), 0.f);
        float delta = (fp - sqrtf(disc)) / n;
        c += delta;
        if (fabsf(delta) < 2e-6f) break;   // block-uniform
    }
#pragma unroll
    for (int u = 0; u < 12; ++u) {
        float zc = fmaxf(w[u] - c, 0.f);
        w[u] = zc * zc;
    }
    rf4[t]       = make_float4(w[0], w[1], w[2],  w[3]);
    rf4[t + 256] = make_float4(w[4], w[5], w[6],  w[7]);
    rf4[t + 512] = make_float4(w[8], w[9], w[10], w[11]);
}

// -------------------- K4: PV = attn @ V (MFMA) --------------------
// grid (48, 2, 8), block 256 = 4 waves; wave = 16 rows x 64 dv; k-split 2.
// A loaded fp32 and packed to bf16 via v_perm_b32 (truncation, 1 inst / 2 elem).
__global__ void pv_kernel(const float* __restrict__ attn, const short* __restrict__ Vt,
                          float* __restrict__ AO) {
    const int mb = blockIdx.x, ks = blockIdx.y, h = blockIdx.z;
    const int t = threadIdx.x;
    const int w = t >> 6, l = t & 63;
    const int lr = l & 15, lk = l >> 4;
    const int arow = mb * 64 + w * 16 + lr;
    const float* Ar = attn + ((size_t)h * S + arow) * S + ks * (S / 2) + lk * 8;
    const short* Vh = Vt + (size_t)h * 64 * S + ks * (S / 2) + lk * 8;

    f32x4 acc[4];
#pragma unroll
    for (int j = 0; j < 4; ++j) acc[j] = (f32x4){0.f, 0.f, 0.f, 0.f};

#pragma unroll 2
    for (int st = 0; st < 48; ++st) {
        const float4* ap = (const float4*)(Ar + st * 32);
        float4 a0 = ap[0], a1 = ap[1];
        union { unsigned u[4]; bf16x8 v; } pk;
        pk.u[0] = pack_bf_trunc(a0.x, a0.y);
        pk.u[1] = pack_bf_trunc(a0.z, a0.w);
        pk.u[2] = pack_bf_trunc(a1.x, a1.y);
        pk.u[3] = pack_bf_trunc(a1.z, a1.w);
#pragma unroll
        for (int j = 0; j < 4; ++j) {
            bf16x8 b = *(const bf16x8*)(Vh + (size_t)(j * 16 + lr) * S + st * 32);
            acc[j] = __builtin_amdgcn_mfma_f32_16x16x32_bf16(pk.v, b, acc[j], 0, 0, 0);
        }
    }
    float* AOk = AO + (size_t)ks * ((size_t)H * S * 64)
                    + ((size_t)h * S + mb * 64 + w * 16) * 64;
#pragma unroll
    for (int j = 0; j < 4; ++j)
#pragma unroll
        for (int r = 0; r < 4; ++r)
            AOk[(size_t)(lk * 4 + r) * 64 + j * 16 + lr] = acc[j][r];
}

// -------------------- K5: out-proj + residual + LayerNorm --------------------
__global__ void outproj_ln_kernel(const float* __restrict__ AO, const float* __restrict__ Wo,
                                  const float* __restrict__ bo, const float* __restrict__ x,
                                  const float* __restrict__ gamma, const float* __restrict__ beta,
                                  float* __restrict__ out) {
    __shared__ float red[8];
    const int rb = blockIdx.x;
    const int t  = threadIdx.x;
    const int s0 = rb * 8;
    float acc0[8] = {}, acc1[8] = {};
    const int c0 = t, c1 = t + 256;
    const float4* A0 = (const float4*)AO;
    const float4* A1 = A0 + (size_t)H * S * 16;
    for (int k4 = 0; k4 < 128; ++k4) {
        int k = k4 * 4;
        int h = k >> 6, d4 = (k & 63) >> 2;
        float w00 = Wo[(k + 0) * 512 + c0], w10 = Wo[(k + 0) * 512 + c1];
        float w01 = Wo[(k + 1) * 512 + c0], w11 = Wo[(k + 1) * 512 + c1];
        float w02 = Wo[(k + 2) * 512 + c0], w12 = Wo[(k + 2) * 512 + c1];
        float w03 = Wo[(k + 3) * 512 + c0], w13 = Wo[(k + 3) * 512 + c1];
#pragma unroll
        for (int r = 0; r < 8; ++r) {
            size_t off = ((size_t)h * S + s0 + r) * 16 + d4;    // uniform
            float4 p = A0[off], q = A1[off];
            float ax = p.x + q.x, ay = p.y + q.y, az = p.z + q.z, aw = p.w + q.w;
            acc0[r] += ax * w00 + ay * w01 + az * w02 + aw * w03;
            acc1[r] += ax * w10 + ay * w11 + az * w12 + aw * w13;
        }
    }
    const float b0 = bo[c0], b1 = bo[c1];
    const float g0 = gamma[c0], g1 = gamma[c1];
    const float be0 = beta[c0], be1 = beta[c1];
    const int wave = t >> 6, lane = t & 63;
    for (int r = 0; r < 8; ++r) {
        float y0 = acc0[r] + b0 + x[(size_t)(s0 + r) * 512 + c0];
        float y1 = acc1[r] + b1 + x[(size_t)(s0 + r) * 512 + c1];
        float s = y0 + y1, qq = y0 * y0 + y1 * y1;
#pragma unroll
        for (int off = 32; off; off >>= 1) {
            s  += __shfl_down(s, off, 64);
            qq += __shfl_down(qq, off, 64);
        }
        __syncthreads();
        if (lane == 0) { red[wave * 2] = s; red[wave * 2 + 1] = qq; }
        __syncthreads();
        s  = red[0] + red[2] + red[4] + red[6];
        qq = red[1] + red[3] + red[5] + red[7];
        float mu  = s * (1.0f / 512.0f);
        float var = qq * (1.0f / 512.0f) - mu * mu;
        float inv = rsqrtf(var + LN_EPS);
        out[(size_t)(s0 + r) * 512 + c0] = (y0 - mu) * inv * g0 + be0;
        out[(size_t)(s0 + r) * 512 + c1] = (y1 - mu) * inv * g1 + be1;
    }
}

extern "C" void kernel_launch(void* const* d_in, const int* in_sizes, int n_in,
                              void* d_out, int out_size, void* d_ws, size_t ws_size,
                              hipStream_t stream) {
    const float* x     = (const float*)d_in[0];
    const float* Wq    = (const float*)d_in[1];
    const float* bq    = (const float*)d_in[2];
    const float* Wk    = (const float*)d_in[3];
    const float* bk    = (const float*)d_in[4];
    const float* Wv    = (const float*)d_in[5];
    const float* bv    = (const float*)d_in[6];
    const float* Wo    = (const float*)d_in[7];
    const float* bo    = (const float*)d_in[8];
    const float* gamma = (const float*)d_in[9];
    const float* beta  = (const float*)d_in[10];

    float* out  = (float*)d_out;
    float* attn = out + (size_t)S * D;          // tuple output #2, logits scratch

    short* Qb = (short*)d_ws;                   // [H][S][64] bf16, pre-scaled
    short* Kb = Qb + (size_t)H * S * 64;        // [H][S][64] bf16
    short* Vt = Kb + (size_t)H * S * 64;        // [H][64][S] bf16 (transposed)
    float* AO = (float*)(Vt + (size_t)H * 64 * S);   // 2 x [H][S][64] f32 partials

    qkv_kernel<<<dim3(S / 8, 6), 256, 0, stream>>>(x, Wq, bq, Wk, bk, Wv, bv, Qb, Kb, Vt);
    logits_kernel<<<dim3(24, 24, 8), 256, 0, stream>>>(Qb, Kb, attn);
    entmax_kernel<<<dim3(S, H), 256, 0, stream>>>(attn);
    pv_kernel<<<dim3(48, 2, 8), 256, 0, stream>>>(attn, Vt, AO);
    outproj_ln_kernel<<<dim3(S / 8), 256, 0, stream>>>(AO, Wo, bo, x, gamma, beta, out);
}